// Round 3
// baseline (2574.897 us; speedup 1.0000x reference)
//
#include <hip/hip_runtime.h>
#include <math.h>

#define BB 128
#define TT 32
#define DDIM 64
#define VV 4096
#define SS 32
#define RR 8
#define NT 512
#define SMP 65   // padded leading dim for s_mem

typedef unsigned short u16;
typedef unsigned int u32;
typedef _Float16 h2 __attribute__((ext_vector_type(2)));

__device__ __forceinline__ h2 bch(u32 u){ union { u32 u; h2 h; } v; v.u = u; return v.h; }

__device__ __forceinline__ float fdot2f(u32 a, u32 b, float acc){
#if __has_builtin(__builtin_amdgcn_fdot2)
  return __builtin_amdgcn_fdot2(bch(a), bch(b), acc, false);
#else
  h2 x = bch(a), y = bch(b);
  return acc + (float)x[0] * (float)y[0] + (float)x[1] * (float)y[1];
#endif
}

__device__ __forceinline__ u32 packh2(float a, float b){
  union { _Float16 h[2]; u32 u; } p;
  p.h[0] = (_Float16)a; p.h[1] = (_Float16)b;
  return p.u;
}

// ---------------- K0a: pack vq_emb into lane-coalesced f16 tiles ----------------
// vqT uint4 index: ((c0*16 + dc8)*64 + l), code c = c0*64+l, dims dc8*8..dc8*8+7 (8 f16)
__global__ __launch_bounds__(256) void k_pack(const float* __restrict__ vq, u32* __restrict__ vqT){
  int gid = blockIdx.x * 256 + threadIdx.x;     // 65536 entries
  int l   = gid & 63;
  int dc8 = (gid >> 6) & 15;
  int c0  = gid >> 10;
  int c   = (c0 << 6) + l;
  const float* s = vq + c * 128 + dc8 * 8;
  uint4 o;
  o.x = packh2(s[0], s[1]);
  o.y = packh2(s[2], s[3]);
  o.z = packh2(s[4], s[5]);
  o.w = packh2(s[6], s[7]);
  ((uint4*)vqT)[gid] = o;
}

// ---------------- K0b: per-code squared norm (exact f32) ----------------
__global__ __launch_bounds__(256) void k_vqsq(const float* __restrict__ vq, float* __restrict__ vqsq){
  int c = blockIdx.x * 256 + threadIdx.x;
  float s = 0.f;
  for (int d = 0; d < 128; d++){ float v = vq[c * 128 + d]; s = fmaf(v, v, s); }
  vqsq[c] = s;
}

// ---------------- K1: the full recurrence, one block per batch row ----------------
__global__ __launch_bounds__(NT) void k_recur(
    const int* __restrict__ x_seq, const float* __restrict__ enc_emb,
    const float* __restrict__ vq_emb, const u32* __restrict__ vqT,
    const float* __restrict__ vq_sq,
    const float* __restrict__ nrg, const float* __restrict__ nrb,
    const float* __restrict__ nig, const float* __restrict__ nib,
    const float* __restrict__ proj_w, const float* __restrict__ proj_b,
    const float* __restrict__ mgw, const float* __restrict__ mgb,
    const float* __restrict__ arb_w, const float* __restrict__ arb_b,
    const float* __restrict__ hb, const float* __restrict__ ig,
    float* __restrict__ gwout, float* __restrict__ flatF,
    int* __restrict__ idxbuf, int* __restrict__ rstop_g, float* __restrict__ accs,
    float* __restrict__ out_mem)
{
  const int b = blockIdx.x;
  const int tid = threadIdx.x;
  const int lane = tid & 63;
  const int wave = tid >> 6;

  __shared__ __align__(16) float s_gw[128];
  __shared__ __align__(16) float s_flat[128];
  __shared__ __align__(16) u32   s_flath[64];   // f16 copy of s_flat (64 half2)
  __shared__ float s_zq[128];
  __shared__ float s_c[128];
  __shared__ float s_mem[2][SS][SMP];           // padded: no stride-64 conflicts
  __shared__ float s_mv[12][DDIM];
  __shared__ float s_qkw[6][DDIM];              // qr,qi,kr,ki,wr,wi
  __shared__ float s_sim[SS];
  __shared__ float s_red[16];
  __shared__ float s_sc[4];                     // 0: gate, 1: vq_loss
  __shared__ int   s_imin;
  __shared__ float s_cand[8];
  __shared__ int   s_candi[8];

  for (int i = tid; i < 128; i += NT) s_gw[i] = 0.f;
  for (int i = tid; i < 2 * SS * SMP; i += NT) ((float*)s_mem)[i] = 0.f;
  __syncthreads();

  const float alpha = 1.f / (1.f + expf(-ig[0]));
  float bias_h; { float x = hb[0]; bias_h = log1pf(expf(x)); }
  int head = 0;
  float prev_ang = 0.f;   // meaningful for wave 0

  for (int t = 0; t < TT; t++){
    int xid = x_seq[b * TT + t];
    if (tid < 128){
      float e = enc_emb[xid * 128 + tid];
      s_gw[tid] = alpha * s_gw[tid] + (1.f - alpha) * e;
    }
    __syncthreads();
    if (wave == 0) prev_ang = atan2f(s_gw[64 + lane], s_gw[lane]);

    float acc_ph = 0.f, acc_vq = 0.f;
    int rst = 0;

    for (int r = 0; r < RR; r++){
      // ---- LayerNorm halves -> s_flat (f32) + s_flath (f16 pairs)
      if (wave < 2){
        float x = s_gw[wave * 64 + lane];
        float mu = x;
        for (int m = 1; m < 64; m <<= 1) mu += __shfl_xor(mu, m);
        mu *= (1.f / 64.f);
        float dxl = x - mu;
        float vv = dxl * dxl;
        for (int m = 1; m < 64; m <<= 1) vv += __shfl_xor(vv, m);
        vv *= (1.f / 64.f);
        float rs = 1.f / sqrtf(vv + 1e-5f);
        const float* g  = wave ? nig : nrg;
        const float* bb = wave ? nib : nrb;
        float fv = dxl * rs * g[lane] + bb[lane];
        s_flat[wave * 64 + lane] = fv;
        float pv = __shfl_xor(fv, 1);
        if ((lane & 1) == 0)
          s_flath[(wave * 64 + lane) >> 1] = packh2(fv, pv);
      }
      __syncthreads();

      // ---- VQ nearest-code search: f16 dots, f32 norms, register-cached flat
      uint4 F[16];
      {
        const uint4* sfh4 = (const uint4*)s_flath;
        #pragma unroll
        for (int i = 0; i < 16; i++) F[i] = sfh4[i];
      }
      float dot[8];
      #pragma unroll
      for (int k = 0; k < 8; k++) dot[k] = 0.f;
      const uint4* vb = ((const uint4*)vqT) + (wave * 16) * 64 + lane;
      #pragma unroll
      for (int dc8 = 0; dc8 < 16; dc8++){
        uint4 f = F[dc8];
        #pragma unroll
        for (int k = 0; k < 8; k++){
          uint4 u = vb[(k * 128 + dc8) * 64];
          float d = dot[k];
          d = fdot2f(u.x, f.x, d);
          d = fdot2f(u.y, f.y, d);
          d = fdot2f(u.z, f.z, d);
          d = fdot2f(u.w, f.w, d);
          dot[k] = d;
        }
      }
      float bsc = 3.4e38f; int bidx = 0;
      #pragma unroll
      for (int k = 0; k < 8; k++){
        int c = (wave + 8 * k) * 64 + lane;
        float sc = vq_sq[c] - 2.f * dot[k];
        if (sc < bsc || (sc == bsc && c < bidx)){ bsc = sc; bidx = c; }
      }
      for (int m = 1; m < 64; m <<= 1){
        float os = __shfl_xor(bsc, m);
        int   oi = __shfl_xor(bidx, m);
        if (os < bsc || (os == bsc && oi < bidx)){ bsc = os; bidx = oi; }
      }
      if (lane == 0){ s_cand[wave] = bsc; s_candi[wave] = bidx; }
      __syncthreads();
      if (tid == 0){
        float bs = s_cand[0]; int bi = s_candi[0];
        for (int w = 1; w < 8; w++){
          float os = s_cand[w]; int oi = s_candi[w];
          if (os < bs || (os == bs && oi < bi)){ bs = os; bi = oi; }
        }
        s_imin = bi;
        idxbuf[(b * TT + t) * RR + r] = bi;
      }
      __syncthreads();
      int imin = s_imin;

      // ---- zq load (exact f32) + vq_loss partials (waves 0,1); matvecs (all waves)
      if (tid < 128){
        float z = vq_emb[imin * 128 + tid];
        s_zq[tid] = z;
        float dv = z - s_flat[tid];
        float sq = dv * dv;
        for (int m = 1; m < 64; m <<= 1) sq += __shfl_xor(sq, m);
        if (lane == 0) s_red[wave] = sq;
      }
      for (int mm = wave; mm < 12; mm += 8){
        int p = mm >> 2, kind = mm & 3;
        int xoff = (kind == 0 || kind == 3) ? 0 : 64;
        int wsel = (kind == 0 || kind == 2) ? 0 : 1;
        const float* W = proj_w + ((p * 2 + wsel) << 12);
        const float4* fx = (const float4*)&s_flat[xoff];
        float a = 0.f;
        #pragma unroll
        for (int i = 0; i < 16; i++){
          float4 fv = fx[i];
          a = fmaf(fv.x, W[(4 * i + 0) * 64 + lane], a);
          a = fmaf(fv.y, W[(4 * i + 1) * 64 + lane], a);
          a = fmaf(fv.z, W[(4 * i + 2) * 64 + lane], a);
          a = fmaf(fv.w, W[(4 * i + 3) * 64 + lane], a);
        }
        s_mv[mm][lane] = a;
      }
      __syncthreads();

      if (tid == 0) s_sc[1] = 1.25f * (s_red[0] + s_red[1]) * (1.f / 128.f);
      // ---- combine to q,k,w (real/imag)
      if (tid < 192){
        int p = tid >> 6, j = tid & 63;
        float A  = s_mv[p * 4 + 0][j];
        float Bv = s_mv[p * 4 + 1][j];
        float C  = s_mv[p * 4 + 2][j];
        float Dv = s_mv[p * 4 + 3][j];
        float br = proj_b[(p * 2 + 0) * 64 + j];
        float bi = proj_b[(p * 2 + 1) * 64 + j];
        s_qkw[p * 2 + 0][j] = A + br - Bv - bi;
        s_qkw[p * 2 + 1][j] = C + br + Dv + bi;
      }
      __syncthreads();

      // ---- gate (wave 0) and attention scores (all)
      if (wave == 0){
        float g = s_qkw[0][lane] * s_qkw[2][lane] + s_qkw[1][lane] * s_qkw[3][lane];
        for (int m = 1; m < 64; m <<= 1) g += __shfl_xor(g, m);
        if (lane == 0) s_sc[0] = 1.f / (1.f + expf(-g));
      }
      {
        int slot = tid >> 4, sub = tid & 15;
        float p = 0.f;
        for (int k = 0; k < 8; k++){
          int dd = sub * 8 + k;
          float mv = (dd < 64) ? s_mem[0][slot][dd] : s_mem[1][slot][dd - 64];
          p = fmaf(mv, s_flat[dd], p);
        }
        for (int m = 1; m < 16; m <<= 1) p += __shfl_xor(p, m, 16);
        if (sub == 0) s_sim[slot] = p;
      }
      __syncthreads();
      // ---- softmax over 32 slots
      if (wave == 0 && lane < 32){
        float v = s_sim[lane];
        float mx = v;
        for (int m = 1; m < 32; m <<= 1) mx = fmaxf(mx, __shfl_xor(mx, m, 32));
        float e = expf(v - mx);
        float sm = e;
        for (int m = 1; m < 32; m <<= 1) sm += __shfl_xor(sm, m, 32);
        s_sim[lane] = e / sm;
      }
      __syncthreads();
      // ---- weighted memory read (threads 0..127) + arbiter logits (waves 2..4)
      float m_reg = 0.f;
      if (tid < 128){
        int h = tid >> 6, d0 = tid & 63;
        for (int s2 = 0; s2 < 32; s2++)
          m_reg = fmaf(s_sim[s2], s_mem[h][s2][d0], m_reg);
      } else if (wave >= 2 && wave < 5){
        int k = wave - 2;
        float p = s_flat[lane] * arb_w[lane * 3 + k]
                + s_flat[64 + lane] * arb_w[(64 + lane) * 3 + k];
        for (int m = 1; m < 64; m <<= 1) p += __shfl_xor(p, m);
        if (lane == 0) s_red[4 + k] = p + arb_b[k];
      }
      __syncthreads();
      // ---- gates softmax + candidate state
      if (tid < 128){
        float l0 = s_red[4], l1 = s_red[5], l2 = s_red[6];
        float mx = fmaxf(l0, fmaxf(l1, l2));
        float e0 = expf(l0 - mx), e1 = expf(l1 - mx), e2 = expf(l2 - mx);
        float inv = 1.f / (e0 + e1 + e2);
        float g0 = e0 * inv, g1 = e1 * inv, g2 = e2 * inv;
        float gate = s_sc[0];
        int h = tid >> 6, j = tid & 63;
        float wv = s_qkw[4 + h][j];
        float u = g0 * (gate * wv) + g1 * m_reg + g2 * s_zq[tid];
        s_c[tid] = 0.6f * s_flat[tid] + 0.4f * u;
      }
      __syncthreads();
      // ---- phase difference (wave 0)
      if (wave == 0){
        float ang = atan2f(s_c[64 + lane], s_c[lane]);
        float df = fabsf(ang - prev_ang);
        df = fminf(df, 6.28318530717958647692f - df);
        prev_ang = ang;
        for (int m = 1; m < 64; m <<= 1) df += __shfl_xor(df, m);
        if (lane == 0) s_red[7] = df * (1.f / 64.f);
      }
      __syncthreads();
      // ---- bookkeeping (uniform across all threads) + state commit
      float vl = s_sc[1];
      acc_ph += s_red[7];
      acc_vq = vl;
      rst = r;
      bool stop = (bias_h - vl) > 0.f;
      if (tid < 128) s_gw[tid] = s_c[tid];
      __syncthreads();
      if (stop) break;
    } // r

    float pond = 0.01f * (float)(rst + 1);
    if (tid < 128) gwout[(b * TT + t) * 128 + tid] = s_gw[tid];
    if (rst < RR - 1 && wave < 2){
      // frozen flat = LN(final gw), for deferred tail-idx search
      float x = s_gw[wave * 64 + lane];
      float mu = x;
      for (int m = 1; m < 64; m <<= 1) mu += __shfl_xor(mu, m);
      mu *= (1.f / 64.f);
      float dxl = x - mu;
      float vv = dxl * dxl;
      for (int m = 1; m < 64; m <<= 1) vv += __shfl_xor(vv, m);
      vv *= (1.f / 64.f);
      float rs = 1.f / sqrtf(vv + 1e-5f);
      const float* g  = wave ? nig : nrg;
      const float* bb = wave ? nib : nrb;
      flatF[(b * TT + t) * 128 + wave * 64 + lane] = dxl * rs * g[lane] + bb[lane];
    }
    if (wave < 2){
      float p = s_gw[wave * 64 + lane] * mgw[wave * 64 + lane];
      for (int m = 1; m < 64; m <<= 1) p += __shfl_xor(p, m);
      if (lane == 0) s_red[8 + wave] = p;
    }
    __syncthreads();
    float wg = 1.f / (1.f + expf(-(s_red[8] + s_red[9] + mgb[0])));
    head = (head + SS - 1) & (SS - 1);
    if (tid < 128){
      int h = tid >> 6, d0 = tid & 63;
      float old = s_mem[h][head][d0];
      s_mem[h][head][d0] = wg * s_gw[tid] + (1.f - wg) * old;
    }
    if (tid == 0){
      int o = b * TT + t;
      rstop_g[o] = rst;
      accs[o * 4 + 0] = acc_vq;
      accs[o * 4 + 1] = pond;
      accs[o * 4 + 2] = acc_ph;
    }
    __syncthreads();
  } // t

  for (int i = tid; i < SS * DDIM; i += NT){
    int s2 = i >> 6, d0 = i & 63;
    int ph = (head + s2) & (SS - 1);
    out_mem[b * SS * DDIM + i] = s_mem[0][ph][d0];
    out_mem[BB * SS * DDIM + b * SS * DDIM + i] = s_mem[1][ph][d0];
  }
}

// ---------------- Kmax: per-timestep max r_stop ----------------
__global__ void k_max(const int* __restrict__ rstop_g, int* __restrict__ maxr){
  int t = threadIdx.x;
  if (t >= TT) return;
  int mx = 0;
  for (int b = 0; b < BB; b++) mx = max(mx, rstop_g[b * TT + t]);
  maxr[t] = mx;
}

// ---------------- K1b: fill frozen tail idx (cold path) ----------------
__global__ __launch_bounds__(256) void k_tail(
    const u32* __restrict__ vqT, const float* __restrict__ vq_sq,
    const float* __restrict__ flatF, const int* __restrict__ rstop_g,
    const int* __restrict__ maxr, int* __restrict__ idxbuf)
{
  int o = blockIdx.x;               // b*TT + t
  int t = o & (TT - 1);
  int rs = rstop_g[o];
  if (rs >= maxr[t]) return;
  __shared__ __align__(16) float sf[128];
  __shared__ __align__(16) u32 sfh[64];
  __shared__ float s_cand[4];
  __shared__ int   s_candi[4];
  int tid = threadIdx.x, lane = tid & 63, wave = tid >> 6;
  if (tid < 128) sf[tid] = flatF[o * 128 + tid];
  __syncthreads();
  if (tid < 64) sfh[tid] = packh2(sf[2 * tid], sf[2 * tid + 1]);
  __syncthreads();
  uint4 F[16];
  {
    const uint4* sfh4 = (const uint4*)sfh;
    #pragma unroll
    for (int i = 0; i < 16; i++) F[i] = sfh4[i];
  }
  float bsc = 3.4e38f; int bidx = 0;
  const uint4* vb = ((const uint4*)vqT) + (wave * 16) * 64 + lane;
  for (int k = 0; k < 16; k++){
    float dot = 0.f;
    #pragma unroll
    for (int dc8 = 0; dc8 < 16; dc8++){
      uint4 u = vb[(k * 64 + dc8) * 64];
      uint4 f = F[dc8];
      dot = fdot2f(u.x, f.x, dot);
      dot = fdot2f(u.y, f.y, dot);
      dot = fdot2f(u.z, f.z, dot);
      dot = fdot2f(u.w, f.w, dot);
    }
    int c = (wave + 4 * k) * 64 + lane;
    float sc = vq_sq[c] - 2.f * dot;
    if (sc < bsc || (sc == bsc && c < bidx)){ bsc = sc; bidx = c; }
  }
  for (int m = 1; m < 64; m <<= 1){
    float os = __shfl_xor(bsc, m);
    int   oi = __shfl_xor(bidx, m);
    if (os < bsc || (os == bsc && oi < bidx)){ bsc = os; bidx = oi; }
  }
  if (lane == 0){ s_cand[wave] = bsc; s_candi[wave] = bidx; }
  __syncthreads();
  if (tid == 0){
    float bs = s_cand[0]; int bi = s_candi[0];
    for (int w = 1; w < 4; w++){
      float os = s_cand[w]; int oi = s_candi[w];
      if (os < bs || (os == bs && oi < bi)){ bs = os; bi = oi; }
    }
    for (int r = rs + 1; r < RR; r++) idxbuf[o * RR + r] = bi;
  }
}

// ---------------- K2: entropy/perplexity + final stats ----------------
__global__ __launch_bounds__(512) void k_stats(
    const int* __restrict__ idxbuf, const int* __restrict__ rstop_g,
    const float* __restrict__ accs, const int* __restrict__ maxr,
    float* __restrict__ out_stats)
{
  __shared__ float s_ent[TT][RR];
  __shared__ int   s_vals[8][128];
  __shared__ float s_fin[8][5];
  int tid = threadIdx.x, lane = tid & 63, wave = tid >> 6;

  for (int base = 0; base < TT * RR; base += 8){
    int p = base + wave;
    int r = p >> 5, t = p & 31;
    bool act = (r <= maxr[t]);
    s_vals[wave][lane]      = idxbuf[(lane * TT + t) * RR + r];
    s_vals[wave][64 + lane] = idxbuf[((64 + lane) * TT + t) * RR + r];
    __syncthreads();
    if (act){
      int mine1 = s_vals[wave][lane], mine2 = s_vals[wave][64 + lane];
      int c1 = 0, c2 = 0;
      for (int j = 0; j < 128; j++){
        int v = s_vals[wave][j];
        c1 += (v == mine1); c2 += (v == mine2);
      }
      float contrib = -(logf((float)c1 * (1.f / 128.f) + 1e-10f)
                      + logf((float)c2 * (1.f / 128.f) + 1e-10f)) * (1.f / 128.f);
      for (int m = 1; m < 64; m <<= 1) contrib += __shfl_xor(contrib, m);
      if (lane == 0) s_ent[t][r] = contrib;
    }
    __syncthreads();
  }

  float sv = 0.f, sp = 0.f, se = 0.f, sn = 0.f, sh = 0.f;
  for (int o = tid; o < BB * TT; o += 512){
    int t = o & 31;
    int rs = rstop_g[o];
    float ent = s_ent[t][rs];
    se += ent;
    sp += expf(ent);
    sv += accs[o * 4 + 0];
    sn += accs[o * 4 + 1];
    sh += accs[o * 4 + 2];
  }
  for (int m = 1; m < 64; m <<= 1){
    sv += __shfl_xor(sv, m); sp += __shfl_xor(sp, m); se += __shfl_xor(se, m);
    sn += __shfl_xor(sn, m); sh += __shfl_xor(sh, m);
  }
  if (lane == 0){
    s_fin[wave][0] = sv; s_fin[wave][1] = sp; s_fin[wave][2] = se;
    s_fin[wave][3] = sn; s_fin[wave][4] = sh;
  }
  __syncthreads();
  if (tid == 0){
    float a[5] = {0.f, 0.f, 0.f, 0.f, 0.f};
    for (int w = 0; w < 8; w++)
      for (int j = 0; j < 5; j++) a[j] += s_fin[w][j];
    float inv = 1.f / (float)(BB * TT);
    for (int j = 0; j < 5; j++) out_stats[j] = a[j] * inv;
  }
}

// ---------------- K3: decoder GEMM  logits = flat_out @ dec_w + dec_b ----------------
__global__ __launch_bounds__(256) void k_dec(
    const float* __restrict__ gwout, const float* __restrict__ dec_w,
    const float* __restrict__ dec_b, float* __restrict__ out)
{
  __shared__ float At[32][128];
  int tid = threadIdx.x;
  int row0 = blockIdx.y * 32;
  int col0 = blockIdx.x * 256;
  {
    const float4* src = (const float4*)(gwout + row0 * 128);
    float4* dst = (float4*)&At[0][0];
    for (int i = tid; i < 1024; i += 256) dst[i] = src[i];
  }
  __syncthreads();
  int v = col0 + tid;
  float acc[32];
  #pragma unroll
  for (int r2 = 0; r2 < 32; r2++) acc[r2] = 0.f;
  for (int k = 0; k < 128; k += 4){
    float w0 = dec_w[(k + 0) * 4096 + v];
    float w1 = dec_w[(k + 1) * 4096 + v];
    float w2 = dec_w[(k + 2) * 4096 + v];
    float w3 = dec_w[(k + 3) * 4096 + v];
    #pragma unroll
    for (int r2 = 0; r2 < 32; r2++){
      float4 a = *(const float4*)&At[r2][k];
      acc[r2] = fmaf(a.x, w0, fmaf(a.y, w1, fmaf(a.z, w2, fmaf(a.w, w3, acc[r2]))));
    }
  }
  float bv = dec_b[v];
  for (int r2 = 0; r2 < 32; r2++)
    out[(row0 + r2) * 4096 + v] = acc[r2] + bv;
}

extern "C" void kernel_launch(void* const* d_in, const int* in_sizes, int n_in,
                              void* d_out, int out_size, void* d_ws, size_t ws_size,
                              hipStream_t stream){
  const int*   x_seq   = (const int*)  d_in[0];
  const float* enc_emb = (const float*)d_in[1];
  const float* vq_emb  = (const float*)d_in[2];
  const float* nrg     = (const float*)d_in[3];
  const float* nrb     = (const float*)d_in[4];
  const float* nig     = (const float*)d_in[5];
  const float* nib     = (const float*)d_in[6];
  const float* proj_w  = (const float*)d_in[7];
  const float* proj_b  = (const float*)d_in[8];
  const float* mgw     = (const float*)d_in[9];
  const float* mgb     = (const float*)d_in[10];
  const float* arb_w   = (const float*)d_in[11];
  const float* arb_b   = (const float*)d_in[12];
  const float* dec_w   = (const float*)d_in[13];
  const float* dec_b   = (const float*)d_in[14];
  const float* hb      = (const float*)d_in[15];
  const float* ig      = (const float*)d_in[16];

  char* ws = (char*)d_ws;
  u32*   vqT    = (u32*)  (ws + 0);            // 1,048,576 B (f16 tiles)
  float* vqsq   = (float*)(ws + 2097152);      //    16,384 B
  float* gwout  = (float*)(ws + 2113536);      // 2,097,152 B
  float* flatF  = (float*)(ws + 4210688);      // 2,097,152 B
  int*   idxbuf = (int*)  (ws + 6307840);      //   131,072 B
  int*   rstop  = (int*)  (ws + 6438912);      //    16,384 B
  float* accs   = (float*)(ws + 6455296);      //    65,536 B
  int*   maxr   = (int*)  (ws + 6520832);      //       128 B

  float* out = (float*)d_out;
  float* out_stats = out + 16777216;           // B*T*V
  float* out_mem   = out + 16777221;           // + 5 stats

  k_pack <<<dim3(256), dim3(256), 0, stream>>>(vq_emb, vqT);
  k_vqsq <<<dim3(16),  dim3(256), 0, stream>>>(vq_emb, vqsq);
  k_recur<<<dim3(BB),  dim3(NT),  0, stream>>>(
      x_seq, enc_emb, vq_emb, vqT, vqsq,
      nrg, nrb, nig, nib, proj_w, proj_b, mgw, mgb, arb_w, arb_b, hb, ig,
      gwout, flatF, idxbuf, rstop, accs, out_mem);
  k_dec  <<<dim3(16, 128), dim3(256), 0, stream>>>(gwout, dec_w, dec_b, out);
  k_max  <<<dim3(1),   dim3(64),  0, stream>>>(rstop, maxr);
  k_tail <<<dim3(BB * TT), dim3(256), 0, stream>>>(vqT, vqsq, flatF, rstop, maxr, idxbuf);
  k_stats<<<dim3(1),   dim3(512), 0, stream>>>(idxbuf, rstop, accs, maxr, out_stats);
}

// Round 4
// 720.655 us; speedup vs baseline: 3.5730x; 3.5730x over previous
//
#include <hip/hip_runtime.h>
#include <math.h>

#define BB 128
#define TT 32
#define DDIM 64
#define VV 4096
#define SS 32
#define RR 8
#define NT 512
#define SMP 65   // padded leading dim for s_mem

typedef unsigned short u16;
typedef unsigned int u32;
typedef _Float16 h2 __attribute__((ext_vector_type(2)));

__device__ __forceinline__ h2 bch(u32 u){ union { u32 u; h2 h; } v; v.u = u; return v.h; }

__device__ __forceinline__ float fdot2f(u32 a, u32 b, float acc){
#if __has_builtin(__builtin_amdgcn_fdot2)
  return __builtin_amdgcn_fdot2(bch(a), bch(b), acc, false);
#else
  h2 x = bch(a), y = bch(b);
  return acc + (float)x[0] * (float)y[0] + (float)x[1] * (float)y[1];
#endif
}

__device__ __forceinline__ u32 packh2(float a, float b){
  union { _Float16 h[2]; u32 u; } p;
  p.h[0] = (_Float16)a; p.h[1] = (_Float16)b;
  return p.u;
}

// ---------------- K0a: pack vq_emb into lane-coalesced f16 tiles ----------------
// vqT uint4 index: ((c0*16 + dc8)*64 + l), code c = c0*64+l, dims dc8*8..dc8*8+7 (8 f16)
__global__ __launch_bounds__(256) void k_pack(const float* __restrict__ vq, u32* __restrict__ vqT){
  int gid = blockIdx.x * 256 + threadIdx.x;     // 65536 entries
  int l   = gid & 63;
  int dc8 = (gid >> 6) & 15;
  int c0  = gid >> 10;
  int c   = (c0 << 6) + l;
  const float* s = vq + c * 128 + dc8 * 8;
  uint4 o;
  o.x = packh2(s[0], s[1]);
  o.y = packh2(s[2], s[3]);
  o.z = packh2(s[4], s[5]);
  o.w = packh2(s[6], s[7]);
  ((uint4*)vqT)[gid] = o;
}

// ---------------- K0b: per-code squared norm (exact f32) ----------------
__global__ __launch_bounds__(256) void k_vqsq(const float* __restrict__ vq, float* __restrict__ vqsq){
  int c = blockIdx.x * 256 + threadIdx.x;
  float s = 0.f;
  for (int d = 0; d < 128; d++){ float v = vq[c * 128 + d]; s = fmaf(v, v, s); }
  vqsq[c] = s;
}

// ---------------- K1: the full recurrence, one block per batch row ----------------
__global__ __launch_bounds__(NT) void k_recur(
    const int* __restrict__ x_seq, const float* __restrict__ enc_emb,
    const float* __restrict__ vq_emb, const u32* __restrict__ vqT,
    const float* __restrict__ vq_sq,
    const float* __restrict__ nrg, const float* __restrict__ nrb,
    const float* __restrict__ nig, const float* __restrict__ nib,
    const float* __restrict__ proj_w, const float* __restrict__ proj_b,
    const float* __restrict__ mgw, const float* __restrict__ mgb,
    const float* __restrict__ arb_w, const float* __restrict__ arb_b,
    const float* __restrict__ hb, const float* __restrict__ ig,
    float* __restrict__ gwout, float* __restrict__ flatF,
    int* __restrict__ idxbuf, int* __restrict__ rstop_g, float* __restrict__ accs,
    float* __restrict__ out_mem)
{
  const int b = blockIdx.x;
  const int tid = threadIdx.x;
  const int lane = tid & 63;
  const int wave = tid >> 6;

  __shared__ __align__(16) float s_gw[128];
  __shared__ __align__(16) float s_flat[128];
  __shared__ __align__(16) u32   s_flath[64];   // f16 copy of s_flat (64 half2)
  __shared__ float s_zq[128];
  __shared__ float s_c[128];
  __shared__ float s_mem[2][SS][SMP];           // padded: no stride-64 conflicts
  __shared__ float s_mv[12][DDIM];
  __shared__ float s_qkw[6][DDIM];              // qr,qi,kr,ki,wr,wi
  __shared__ float s_sim[SS];
  __shared__ float s_red[16];
  __shared__ float s_sc[4];                     // 0: gate, 1: vq_loss
  __shared__ int   s_imin;
  __shared__ float s_cand[8];
  __shared__ int   s_candi[8];

  for (int i = tid; i < 128; i += NT) s_gw[i] = 0.f;
  for (int i = tid; i < 2 * SS * SMP; i += NT) ((float*)s_mem)[i] = 0.f;
  __syncthreads();

  const float alpha = 1.f / (1.f + expf(-ig[0]));
  float bias_h; { float x = hb[0]; bias_h = log1pf(expf(x)); }
  int head = 0;
  float prev_ang = 0.f;   // meaningful for wave 0

  for (int t = 0; t < TT; t++){
    int xid = x_seq[b * TT + t];
    if (tid < 128){
      float e = enc_emb[xid * 128 + tid];
      s_gw[tid] = alpha * s_gw[tid] + (1.f - alpha) * e;
    }
    __syncthreads();
    if (wave == 0) prev_ang = atan2f(s_gw[64 + lane], s_gw[lane]);

    float acc_ph = 0.f, acc_vq = 0.f;
    int rst = 0;

    for (int r = 0; r < RR; r++){
      // ---- LayerNorm halves -> s_flat (f32) + s_flath (f16 pairs)
      if (wave < 2){
        float x = s_gw[wave * 64 + lane];
        float mu = x;
        for (int m = 1; m < 64; m <<= 1) mu += __shfl_xor(mu, m);
        mu *= (1.f / 64.f);
        float dxl = x - mu;
        float vv = dxl * dxl;
        for (int m = 1; m < 64; m <<= 1) vv += __shfl_xor(vv, m);
        vv *= (1.f / 64.f);
        float rs = 1.f / sqrtf(vv + 1e-5f);
        const float* g  = wave ? nig : nrg;
        const float* bb = wave ? nib : nrb;
        float fv = dxl * rs * g[lane] + bb[lane];
        s_flat[wave * 64 + lane] = fv;
        float pv = __shfl_xor(fv, 1);
        if ((lane & 1) == 0)
          s_flath[(wave * 64 + lane) >> 1] = packh2(fv, pv);
      }
      __syncthreads();

      // ---- VQ nearest-code search: f16 dots, f32 norms, register-cached flat.
      // k OUTER (serial): each wave walks contiguous 16 KB windows (c0 = wave+8k),
      // the block's 8 waves cover one contiguous 128 KB region per k-step.
      // (R3's dc8-outer 8-stream interleave blew FETCH to 1.5 GB — don't.)
      uint4 F[16];
      {
        const uint4* sfh4 = (const uint4*)s_flath;
        #pragma unroll
        for (int i = 0; i < 16; i++) F[i] = sfh4[i];
      }
      float bsc = 3.4e38f; int bidx = 0;
      #pragma unroll 1
      for (int k = 0; k < 8; k++){
        int c0 = wave + 8 * k;
        const uint4* vp = ((const uint4*)vqT) + (c0 * 16) * 64 + lane;
        uint4 U[16];
        #pragma unroll
        for (int dc8 = 0; dc8 < 16; dc8++) U[dc8] = vp[dc8 * 64];
        float dot = 0.f;
        #pragma unroll
        for (int dc8 = 0; dc8 < 16; dc8++){
          dot = fdot2f(U[dc8].x, F[dc8].x, dot);
          dot = fdot2f(U[dc8].y, F[dc8].y, dot);
          dot = fdot2f(U[dc8].z, F[dc8].z, dot);
          dot = fdot2f(U[dc8].w, F[dc8].w, dot);
        }
        int c = c0 * 64 + lane;
        float sc = vq_sq[c] - 2.f * dot;
        if (sc < bsc || (sc == bsc && c < bidx)){ bsc = sc; bidx = c; }
      }
      for (int m = 1; m < 64; m <<= 1){
        float os = __shfl_xor(bsc, m);
        int   oi = __shfl_xor(bidx, m);
        if (os < bsc || (os == bsc && oi < bidx)){ bsc = os; bidx = oi; }
      }
      if (lane == 0){ s_cand[wave] = bsc; s_candi[wave] = bidx; }
      __syncthreads();
      if (tid == 0){
        float bs = s_cand[0]; int bi = s_candi[0];
        for (int w = 1; w < 8; w++){
          float os = s_cand[w]; int oi = s_candi[w];
          if (os < bs || (os == bs && oi < bi)){ bs = os; bi = oi; }
        }
        s_imin = bi;
        idxbuf[(b * TT + t) * RR + r] = bi;
      }
      __syncthreads();
      int imin = s_imin;

      // ---- zq load (exact f32) + vq_loss partials (waves 0,1); matvecs (all waves)
      if (tid < 128){
        float z = vq_emb[imin * 128 + tid];
        s_zq[tid] = z;
        float dv = z - s_flat[tid];
        float sq = dv * dv;
        for (int m = 1; m < 64; m <<= 1) sq += __shfl_xor(sq, m);
        if (lane == 0) s_red[wave] = sq;
      }
      for (int mm = wave; mm < 12; mm += 8){
        int p = mm >> 2, kind = mm & 3;
        int xoff = (kind == 0 || kind == 3) ? 0 : 64;
        int wsel = (kind == 0 || kind == 2) ? 0 : 1;
        const float* W = proj_w + ((p * 2 + wsel) << 12);
        const float4* fx = (const float4*)&s_flat[xoff];
        float a = 0.f;
        #pragma unroll
        for (int i = 0; i < 16; i++){
          float4 fv = fx[i];
          a = fmaf(fv.x, W[(4 * i + 0) * 64 + lane], a);
          a = fmaf(fv.y, W[(4 * i + 1) * 64 + lane], a);
          a = fmaf(fv.z, W[(4 * i + 2) * 64 + lane], a);
          a = fmaf(fv.w, W[(4 * i + 3) * 64 + lane], a);
        }
        s_mv[mm][lane] = a;
      }
      __syncthreads();

      if (tid == 0) s_sc[1] = 1.25f * (s_red[0] + s_red[1]) * (1.f / 128.f);
      // ---- combine to q,k,w (real/imag)
      if (tid < 192){
        int p = tid >> 6, j = tid & 63;
        float A  = s_mv[p * 4 + 0][j];
        float Bv = s_mv[p * 4 + 1][j];
        float C  = s_mv[p * 4 + 2][j];
        float Dv = s_mv[p * 4 + 3][j];
        float br = proj_b[(p * 2 + 0) * 64 + j];
        float bi = proj_b[(p * 2 + 1) * 64 + j];
        s_qkw[p * 2 + 0][j] = A + br - Bv - bi;
        s_qkw[p * 2 + 1][j] = C + br + Dv + bi;
      }
      __syncthreads();

      // ---- gate (wave 0) and attention scores (all)
      if (wave == 0){
        float g = s_qkw[0][lane] * s_qkw[2][lane] + s_qkw[1][lane] * s_qkw[3][lane];
        for (int m = 1; m < 64; m <<= 1) g += __shfl_xor(g, m);
        if (lane == 0) s_sc[0] = 1.f / (1.f + expf(-g));
      }
      {
        int slot = tid >> 4, sub = tid & 15;
        float p = 0.f;
        for (int k = 0; k < 8; k++){
          int dd = sub * 8 + k;
          float mv = (dd < 64) ? s_mem[0][slot][dd] : s_mem[1][slot][dd - 64];
          p = fmaf(mv, s_flat[dd], p);
        }
        for (int m = 1; m < 16; m <<= 1) p += __shfl_xor(p, m, 16);
        if (sub == 0) s_sim[slot] = p;
      }
      __syncthreads();
      // ---- softmax over 32 slots
      if (wave == 0 && lane < 32){
        float v = s_sim[lane];
        float mx = v;
        for (int m = 1; m < 32; m <<= 1) mx = fmaxf(mx, __shfl_xor(mx, m, 32));
        float e = expf(v - mx);
        float sm = e;
        for (int m = 1; m < 32; m <<= 1) sm += __shfl_xor(sm, m, 32);
        s_sim[lane] = e / sm;
      }
      __syncthreads();
      // ---- weighted memory read (threads 0..127) + arbiter logits (waves 2..4)
      float m_reg = 0.f;
      if (tid < 128){
        int h = tid >> 6, d0 = tid & 63;
        for (int s2 = 0; s2 < 32; s2++)
          m_reg = fmaf(s_sim[s2], s_mem[h][s2][d0], m_reg);
      } else if (wave >= 2 && wave < 5){
        int k = wave - 2;
        float p = s_flat[lane] * arb_w[lane * 3 + k]
                + s_flat[64 + lane] * arb_w[(64 + lane) * 3 + k];
        for (int m = 1; m < 64; m <<= 1) p += __shfl_xor(p, m);
        if (lane == 0) s_red[4 + k] = p + arb_b[k];
      }
      __syncthreads();
      // ---- gates softmax + candidate state
      if (tid < 128){
        float l0 = s_red[4], l1 = s_red[5], l2 = s_red[6];
        float mx = fmaxf(l0, fmaxf(l1, l2));
        float e0 = expf(l0 - mx), e1 = expf(l1 - mx), e2 = expf(l2 - mx);
        float inv = 1.f / (e0 + e1 + e2);
        float g0 = e0 * inv, g1 = e1 * inv, g2 = e2 * inv;
        float gate = s_sc[0];
        int h = tid >> 6, j = tid & 63;
        float wv = s_qkw[4 + h][j];
        float u = g0 * (gate * wv) + g1 * m_reg + g2 * s_zq[tid];
        s_c[tid] = 0.6f * s_flat[tid] + 0.4f * u;
      }
      __syncthreads();
      // ---- phase difference (wave 0)
      if (wave == 0){
        float ang = atan2f(s_c[64 + lane], s_c[lane]);
        float df = fabsf(ang - prev_ang);
        df = fminf(df, 6.28318530717958647692f - df);
        prev_ang = ang;
        for (int m = 1; m < 64; m <<= 1) df += __shfl_xor(df, m);
        if (lane == 0) s_red[7] = df * (1.f / 64.f);
      }
      __syncthreads();
      // ---- bookkeeping (uniform across all threads) + state commit
      float vl = s_sc[1];
      acc_ph += s_red[7];
      acc_vq = vl;
      rst = r;
      bool stop = (bias_h - vl) > 0.f;
      if (tid < 128) s_gw[tid] = s_c[tid];
      __syncthreads();
      if (stop) break;
    } // r

    float pond = 0.01f * (float)(rst + 1);
    if (tid < 128) gwout[(b * TT + t) * 128 + tid] = s_gw[tid];
    if (rst < RR - 1 && wave < 2){
      // frozen flat = LN(final gw), for deferred tail-idx search
      float x = s_gw[wave * 64 + lane];
      float mu = x;
      for (int m = 1; m < 64; m <<= 1) mu += __shfl_xor(mu, m);
      mu *= (1.f / 64.f);
      float dxl = x - mu;
      float vv = dxl * dxl;
      for (int m = 1; m < 64; m <<= 1) vv += __shfl_xor(vv, m);
      vv *= (1.f / 64.f);
      float rs = 1.f / sqrtf(vv + 1e-5f);
      const float* g  = wave ? nig : nrg;
      const float* bb = wave ? nib : nrb;
      flatF[(b * TT + t) * 128 + wave * 64 + lane] = dxl * rs * g[lane] + bb[lane];
    }
    if (wave < 2){
      float p = s_gw[wave * 64 + lane] * mgw[wave * 64 + lane];
      for (int m = 1; m < 64; m <<= 1) p += __shfl_xor(p, m);
      if (lane == 0) s_red[8 + wave] = p;
    }
    __syncthreads();
    float wg = 1.f / (1.f + expf(-(s_red[8] + s_red[9] + mgb[0])));
    head = (head + SS - 1) & (SS - 1);
    if (tid < 128){
      int h = tid >> 6, d0 = tid & 63;
      float old = s_mem[h][head][d0];
      s_mem[h][head][d0] = wg * s_gw[tid] + (1.f - wg) * old;
    }
    if (tid == 0){
      int o = b * TT + t;
      rstop_g[o] = rst;
      accs[o * 4 + 0] = acc_vq;
      accs[o * 4 + 1] = pond;
      accs[o * 4 + 2] = acc_ph;
    }
    __syncthreads();
  } // t

  for (int i = tid; i < SS * DDIM; i += NT){
    int s2 = i >> 6, d0 = i & 63;
    int ph = (head + s2) & (SS - 1);
    out_mem[b * SS * DDIM + i] = s_mem[0][ph][d0];
    out_mem[BB * SS * DDIM + b * SS * DDIM + i] = s_mem[1][ph][d0];
  }
}

// ---------------- Kmax: per-timestep max r_stop ----------------
__global__ void k_max(const int* __restrict__ rstop_g, int* __restrict__ maxr){
  int t = threadIdx.x;
  if (t >= TT) return;
  int mx = 0;
  for (int b = 0; b < BB; b++) mx = max(mx, rstop_g[b * TT + t]);
  maxr[t] = mx;
}

// ---------------- K1b: fill frozen tail idx (cold path) ----------------
__global__ __launch_bounds__(256) void k_tail(
    const u32* __restrict__ vqT, const float* __restrict__ vq_sq,
    const float* __restrict__ flatF, const int* __restrict__ rstop_g,
    const int* __restrict__ maxr, int* __restrict__ idxbuf)
{
  int o = blockIdx.x;               // b*TT + t
  int t = o & (TT - 1);
  int rs = rstop_g[o];
  if (rs >= maxr[t]) return;
  __shared__ __align__(16) float sf[128];
  __shared__ __align__(16) u32 sfh[64];
  __shared__ float s_cand[4];
  __shared__ int   s_candi[4];
  int tid = threadIdx.x, lane = tid & 63, wave = tid >> 6;
  if (tid < 128) sf[tid] = flatF[o * 128 + tid];
  __syncthreads();
  if (tid < 64) sfh[tid] = packh2(sf[2 * tid], sf[2 * tid + 1]);
  __syncthreads();
  uint4 F[16];
  {
    const uint4* sfh4 = (const uint4*)sfh;
    #pragma unroll
    for (int i = 0; i < 16; i++) F[i] = sfh4[i];
  }
  float bsc = 3.4e38f; int bidx = 0;
  #pragma unroll 1
  for (int k = 0; k < 16; k++){
    int c0 = wave + 4 * k;
    const uint4* vp = ((const uint4*)vqT) + (c0 * 16) * 64 + lane;
    uint4 U[16];
    #pragma unroll
    for (int dc8 = 0; dc8 < 16; dc8++) U[dc8] = vp[dc8 * 64];
    float dot = 0.f;
    #pragma unroll
    for (int dc8 = 0; dc8 < 16; dc8++){
      dot = fdot2f(U[dc8].x, F[dc8].x, dot);
      dot = fdot2f(U[dc8].y, F[dc8].y, dot);
      dot = fdot2f(U[dc8].z, F[dc8].z, dot);
      dot = fdot2f(U[dc8].w, F[dc8].w, dot);
    }
    int c = c0 * 64 + lane;
    float sc = vq_sq[c] - 2.f * dot;
    if (sc < bsc || (sc == bsc && c < bidx)){ bsc = sc; bidx = c; }
  }
  for (int m = 1; m < 64; m <<= 1){
    float os = __shfl_xor(bsc, m);
    int   oi = __shfl_xor(bidx, m);
    if (os < bsc || (os == bsc && oi < bidx)){ bsc = os; bidx = oi; }
  }
  if (lane == 0){ s_cand[wave] = bsc; s_candi[wave] = bidx; }
  __syncthreads();
  if (tid == 0){
    float bs = s_cand[0]; int bi = s_candi[0];
    for (int w = 1; w < 4; w++){
      float os = s_cand[w]; int oi = s_candi[w];
      if (os < bs || (os == bs && oi < bi)){ bs = os; bi = oi; }
    }
    for (int r = rs + 1; r < RR; r++) idxbuf[o * RR + r] = bi;
  }
}

// ---------------- K2: entropy/perplexity + final stats ----------------
__global__ __launch_bounds__(512) void k_stats(
    const int* __restrict__ idxbuf, const int* __restrict__ rstop_g,
    const float* __restrict__ accs, const int* __restrict__ maxr,
    float* __restrict__ out_stats)
{
  __shared__ float s_ent[TT][RR];
  __shared__ int   s_vals[8][128];
  __shared__ float s_fin[8][5];
  int tid = threadIdx.x, lane = tid & 63, wave = tid >> 6;

  for (int base = 0; base < TT * RR; base += 8){
    int p = base + wave;
    int r = p >> 5, t = p & 31;
    bool act = (r <= maxr[t]);
    s_vals[wave][lane]      = idxbuf[(lane * TT + t) * RR + r];
    s_vals[wave][64 + lane] = idxbuf[((64 + lane) * TT + t) * RR + r];
    __syncthreads();
    if (act){
      int mine1 = s_vals[wave][lane], mine2 = s_vals[wave][64 + lane];
      int c1 = 0, c2 = 0;
      for (int j = 0; j < 128; j++){
        int v = s_vals[wave][j];
        c1 += (v == mine1); c2 += (v == mine2);
      }
      float contrib = -(logf((float)c1 * (1.f / 128.f) + 1e-10f)
                      + logf((float)c2 * (1.f / 128.f) + 1e-10f)) * (1.f / 128.f);
      for (int m = 1; m < 64; m <<= 1) contrib += __shfl_xor(contrib, m);
      if (lane == 0) s_ent[t][r] = contrib;
    }
    __syncthreads();
  }

  float sv = 0.f, sp = 0.f, se = 0.f, sn = 0.f, sh = 0.f;
  for (int o = tid; o < BB * TT; o += 512){
    int t = o & 31;
    int rs = rstop_g[o];
    float ent = s_ent[t][rs];
    se += ent;
    sp += expf(ent);
    sv += accs[o * 4 + 0];
    sn += accs[o * 4 + 1];
    sh += accs[o * 4 + 2];
  }
  for (int m = 1; m < 64; m <<= 1){
    sv += __shfl_xor(sv, m); sp += __shfl_xor(sp, m); se += __shfl_xor(se, m);
    sn += __shfl_xor(sn, m); sh += __shfl_xor(sh, m);
  }
  if (lane == 0){
    s_fin[wave][0] = sv; s_fin[wave][1] = sp; s_fin[wave][2] = se;
    s_fin[wave][3] = sn; s_fin[wave][4] = sh;
  }
  __syncthreads();
  if (tid == 0){
    float a[5] = {0.f, 0.f, 0.f, 0.f, 0.f};
    for (int w = 0; w < 8; w++)
      for (int j = 0; j < 5; j++) a[j] += s_fin[w][j];
    float inv = 1.f / (float)(BB * TT);
    for (int j = 0; j < 5; j++) out_stats[j] = a[j] * inv;
  }
}

// ---------------- K3: decoder GEMM  logits = flat_out @ dec_w + dec_b ----------------
__global__ __launch_bounds__(256) void k_dec(
    const float* __restrict__ gwout, const float* __restrict__ dec_w,
    const float* __restrict__ dec_b, float* __restrict__ out)
{
  __shared__ float At[32][128];
  int tid = threadIdx.x;
  int row0 = blockIdx.y * 32;
  int col0 = blockIdx.x * 256;
  {
    const float4* src = (const float4*)(gwout + row0 * 128);
    float4* dst = (float4*)&At[0][0];
    for (int i = tid; i < 1024; i += 256) dst[i] = src[i];
  }
  __syncthreads();
  int v = col0 + tid;
  float acc[32];
  #pragma unroll
  for (int r2 = 0; r2 < 32; r2++) acc[r2] = 0.f;
  for (int k = 0; k < 128; k += 4){
    float w0 = dec_w[(k + 0) * 4096 + v];
    float w1 = dec_w[(k + 1) * 4096 + v];
    float w2 = dec_w[(k + 2) * 4096 + v];
    float w3 = dec_w[(k + 3) * 4096 + v];
    #pragma unroll
    for (int r2 = 0; r2 < 32; r2++){
      float4 a = *(const float4*)&At[r2][k];
      acc[r2] = fmaf(a.x, w0, fmaf(a.y, w1, fmaf(a.z, w2, fmaf(a.w, w3, acc[r2]))));
    }
  }
  float bv = dec_b[v];
  for (int r2 = 0; r2 < 32; r2++)
    out[(row0 + r2) * 4096 + v] = acc[r2] + bv;
}

extern "C" void kernel_launch(void* const* d_in, const int* in_sizes, int n_in,
                              void* d_out, int out_size, void* d_ws, size_t ws_size,
                              hipStream_t stream){
  const int*   x_seq   = (const int*)  d_in[0];
  const float* enc_emb = (const float*)d_in[1];
  const float* vq_emb  = (const float*)d_in[2];
  const float* nrg     = (const float*)d_in[3];
  const float* nrb     = (const float*)d_in[4];
  const float* nig     = (const float*)d_in[5];
  const float* nib     = (const float*)d_in[6];
  const float* proj_w  = (const float*)d_in[7];
  const float* proj_b  = (const float*)d_in[8];
  const float* mgw     = (const float*)d_in[9];
  const float* mgb     = (const float*)d_in[10];
  const float* arb_w   = (const float*)d_in[11];
  const float* arb_b   = (const float*)d_in[12];
  const float* dec_w   = (const float*)d_in[13];
  const float* dec_b   = (const float*)d_in[14];
  const float* hb      = (const float*)d_in[15];
  const float* ig      = (const float*)d_in[16];

  char* ws = (char*)d_ws;
  u32*   vqT    = (u32*)  (ws + 0);            // 1,048,576 B (f16 tiles)
  float* vqsq   = (float*)(ws + 2097152);      //    16,384 B
  float* gwout  = (float*)(ws + 2113536);      // 2,097,152 B
  float* flatF  = (float*)(ws + 4210688);      // 2,097,152 B
  int*   idxbuf = (int*)  (ws + 6307840);      //   131,072 B
  int*   rstop  = (int*)  (ws + 6438912);      //    16,384 B
  float* accs   = (float*)(ws + 6455296);      //    65,536 B
  int*   maxr   = (int*)  (ws + 6520832);      //       128 B

  float* out = (float*)d_out;
  float* out_stats = out + 16777216;           // B*T*V
  float* out_mem   = out + 16777221;           // + 5 stats

  k_pack <<<dim3(256), dim3(256), 0, stream>>>(vq_emb, vqT);
  k_vqsq <<<dim3(16),  dim3(256), 0, stream>>>(vq_emb, vqsq);
  k_recur<<<dim3(BB),  dim3(NT),  0, stream>>>(
      x_seq, enc_emb, vq_emb, vqT, vqsq,
      nrg, nrb, nig, nib, proj_w, proj_b, mgw, mgb, arb_w, arb_b, hb, ig,
      gwout, flatF, idxbuf, rstop, accs, out_mem);
  k_dec  <<<dim3(16, 128), dim3(256), 0, stream>>>(gwout, dec_w, dec_b, out);
  k_max  <<<dim3(1),   dim3(64),  0, stream>>>(rstop, maxr);
  k_tail <<<dim3(BB * TT), dim3(256), 0, stream>>>(vqT, vqsq, flatF, rstop, maxr, idxbuf);
  k_stats<<<dim3(1),   dim3(512), 0, stream>>>(idxbuf, rstop, accs, maxr, out_stats);
}